// Round 1
// baseline (319.880 us; speedup 1.0000x reference)
//
#include <hip/hip_runtime.h>
#include <stdint.h>

typedef unsigned short u16;
typedef __attribute__((ext_vector_type(4))) float f32x4;
typedef __attribute__((ext_vector_type(8))) __bf16 bf16x8;
typedef __attribute__((ext_vector_type(8))) unsigned short u16x8;
typedef __attribute__((ext_vector_type(4))) unsigned short u16x4;

#define DIM_    1024
#define NHEADS_ 16
#define HD_     64
#define BB_     2
#define NN_     2048
#define MM_     2048

__device__ inline u16 f32_to_bf16u(float f) {
  union { float f; uint32_t u; } x; x.f = f;
  uint32_t r = x.u + 0x7FFFu + ((x.u >> 16) & 1u);
  return (u16)(r >> 16);
}
__device__ inline float bf16u_to_f32(u16 h) {
  union { uint32_t u; float f; } x; x.u = ((uint32_t)h) << 16;
  return x.f;
}

__device__ inline void gload_lds16(const u16* g, u16* l) {
  u16* gnc = const_cast<u16*>(g);
  __builtin_amdgcn_global_load_lds(
      (__attribute__((address_space(1))) void*)gnc,
      (__attribute__((address_space(3))) void*)l, 16, 0, 0);
}

// ---------------- cast fp32 -> bf16 (vectorized) ----------------
__global__ void cast_f32_bf16(const float* __restrict__ src, u16* __restrict__ dst, int n4) {
  int i = blockIdx.x * blockDim.x + threadIdx.x;
  int stride = gridDim.x * blockDim.x;
  for (; i < n4; i += stride) {
    float4 f = reinterpret_cast<const float4*>(src)[i];
    u16x4 u;
    u.x = f32_to_bf16u(f.x);
    u.y = f32_to_bf16u(f.y);
    u.z = f32_to_bf16u(f.z);
    u.w = f32_to_bf16u(f.w);
    reinterpret_cast<u16x4*>(dst)[i] = u;
  }
}

// ---------------- GEMM: C[M,N] = A[M,K] (bf16) * B[N,K]^T (bf16) + bias[N] ----------------
// 128x128 tile, BK=64, 4 waves (2x2), each wave 64x64 via 4x4 frags of 16x16x32 MFMA.
#define BM 128
#define BN 128
#define BK 64

template <bool BF16OUT>
__global__ __launch_bounds__(256)
void gemm_bt(const u16* __restrict__ A, const u16* __restrict__ Bm,
             const float* __restrict__ bias, void* __restrict__ Cout,
             int M, int N, int K) {
  __shared__ __align__(16) u16 As[BM * BK];
  __shared__ __align__(16) u16 Bs[BN * BK];
  const int tid  = threadIdx.x;
  const int lane = tid & 63;
  const int wid  = tid >> 6;
  const int wr = wid >> 1, wc = wid & 1;
  const int fr = lane & 15, fq = lane >> 4;
  const int bm = blockIdx.x, bn = blockIdx.y;
  const int lrow = lane >> 3;        // 0..7 row within 8-row chunk
  const int lcol = (lane & 7) * 8;   // element col, 0..56

  f32x4 acc[4][4];
  #pragma unroll
  for (int m = 0; m < 4; ++m)
    #pragma unroll
    for (int n = 0; n < 4; ++n)
      acc[m][n] = f32x4{0.f, 0.f, 0.f, 0.f};

  for (int k0 = 0; k0 < K; k0 += BK) {
    // stage A and B tiles: 16 KB each; per wave 4 chunks of 1 KB (8 rows x 128B)
    #pragma unroll
    for (int c = 0; c < 4; ++c) {
      int ch  = wid * 4 + c;           // 0..15
      int row = ch * 8 + lrow;         // 0..127
      gload_lds16(A  + (size_t)(bm * BM + row) * K + k0 + lcol, &As[ch * 512]);
      gload_lds16(Bm + (size_t)(bn * BN + row) * K + k0 + lcol, &Bs[ch * 512]);
    }
    __syncthreads();  // drains vmcnt -> LDS ready

    #pragma unroll
    for (int ks = 0; ks < 2; ++ks) {
      bf16x8 af[4], bfr[4];
      #pragma unroll
      for (int m = 0; m < 4; ++m)
        af[m] = *reinterpret_cast<const bf16x8*>(&As[(wr * 64 + m * 16 + fr) * BK + ks * 32 + fq * 8]);
      #pragma unroll
      for (int n = 0; n < 4; ++n)
        bfr[n] = *reinterpret_cast<const bf16x8*>(&Bs[(wc * 64 + n * 16 + fr) * BK + ks * 32 + fq * 8]);
      #pragma unroll
      for (int m = 0; m < 4; ++m)
        #pragma unroll
        for (int n = 0; n < 4; ++n)
          acc[m][n] = __builtin_amdgcn_mfma_f32_16x16x32_bf16(af[m], bfr[n], acc[m][n], 0, 0, 0);
    }
    __syncthreads();  // reads done before next stage
  }

  // epilogue: D[row=fq*4+i][col=fr] per 16x16 frag
  #pragma unroll
  for (int n = 0; n < 4; ++n) {
    int col = bn * BN + wc * 64 + n * 16 + fr;
    float bv = bias[col];
    #pragma unroll
    for (int m = 0; m < 4; ++m) {
      #pragma unroll
      for (int i = 0; i < 4; ++i) {
        int row = bm * BM + wr * 64 + m * 16 + fq * 4 + i;
        float v = acc[m][n][i] + bv;
        if (BF16OUT)
          ((u16*)Cout)[(size_t)row * N + col] = f32_to_bf16u(v);
        else
          ((float*)Cout)[(size_t)row * N + col] = v;
      }
    }
  }
}

// ---------------- flash attention ----------------
// grid: (NN/64, NHEADS, BB); 256 threads = 4 waves; each wave owns 16 q-rows.
// KV tile = 64. K staged [kv][64] via global_load_lds; V staged transposed [d][kv].
#define QB 64
#define KVB 64

__global__ __launch_bounds__(256)
void attn_fwd(const u16* __restrict__ qg, const u16* __restrict__ kg,
              const u16* __restrict__ vg, u16* __restrict__ og) {
  __shared__ __align__(16) u16 Ks[KVB * HD_];
  __shared__ __align__(16) u16 VTs[HD_ * KVB];
  __shared__ __align__(16) u16 Ps[4][16 * KVB];
  const int tid = threadIdx.x, lane = tid & 63, wid = tid >> 6;
  const int fr = lane & 15, fq = lane >> 4;
  const int b = blockIdx.z, h = blockIdx.y;
  const int q0 = blockIdx.x * QB + wid * 16;
  const size_t base_q  = (size_t)b * NN_ * DIM_ + (size_t)h * HD_;
  const size_t base_kv = (size_t)b * MM_ * DIM_ + (size_t)h * HD_;
  const int lrow = lane >> 3, lcol = (lane & 7) * 8;
  const float scale = 0.125f;  // 1/sqrt(64)

  // Q fragments in registers: rows q0+fr, cols ks*32 + fq*8 + j
  bf16x8 qf[2];
  #pragma unroll
  for (int ks = 0; ks < 2; ++ks)
    qf[ks] = *reinterpret_cast<const bf16x8*>(qg + base_q + (size_t)(q0 + fr) * DIM_ + ks * 32 + fq * 8);

  float m_run[4] = {-INFINITY, -INFINITY, -INFINITY, -INFINITY};
  float l_run[4] = {0.f, 0.f, 0.f, 0.f};
  f32x4 oacc[4];
  #pragma unroll
  for (int db = 0; db < 4; ++db) oacc[db] = f32x4{0.f, 0.f, 0.f, 0.f};

  for (int kv0 = 0; kv0 < MM_; kv0 += KVB) {
    // stage K: 8 KB, per wave 2 chunks of 1 KB
    #pragma unroll
    for (int c = 0; c < 2; ++c) {
      int ch  = wid * 2 + c;   // 0..7
      int row = ch * 8 + lrow; // 0..63
      gload_lds16(kg + base_kv + (size_t)(kv0 + row) * DIM_ + lcol, &Ks[ch * 512]);
    }
    // stage V transposed: coalesced 16B global read, scalar LDS scatter
    #pragma unroll
    for (int half = 0; half < 2; ++half) {
      int r  = (tid >> 3) + half * 32; // 0..63
      int c0 = (tid & 7) * 8;          // 0..56
      u16x8 vv = *reinterpret_cast<const u16x8*>(vg + base_kv + (size_t)(kv0 + r) * DIM_ + c0);
      #pragma unroll
      for (int j = 0; j < 8; ++j) VTs[(c0 + j) * KVB + r] = vv[j];
    }
    __syncthreads();

    // QK^T: S[q=fq*4+i][kv=nb*16+fr]
    f32x4 s[4];
    #pragma unroll
    for (int nb = 0; nb < 4; ++nb) s[nb] = f32x4{0.f, 0.f, 0.f, 0.f};
    #pragma unroll
    for (int nb = 0; nb < 4; ++nb)
      #pragma unroll
      for (int ks = 0; ks < 2; ++ks) {
        bf16x8 kf = *reinterpret_cast<const bf16x8*>(&Ks[(nb * 16 + fr) * HD_ + ks * 32 + fq * 8]);
        s[nb] = __builtin_amdgcn_mfma_f32_16x16x32_bf16(qf[ks], kf, s[nb], 0, 0, 0);
      }

    // online softmax (per lane: 4 rows fq*4+i, cols fr+16*nb)
    u16* Pw = Ps[wid];
    #pragma unroll
    for (int i = 0; i < 4; ++i) {
      float mx = fmaxf(fmaxf(s[0][i], s[1][i]), fmaxf(s[2][i], s[3][i])) * scale;
      #pragma unroll
      for (int d = 1; d < 16; d <<= 1) mx = fmaxf(mx, __shfl_xor(mx, d, 64));
      float mnew = fmaxf(m_run[i], mx);
      float corr = __expf(m_run[i] - mnew);
      m_run[i] = mnew;
      float rs = 0.f;
      #pragma unroll
      for (int nb = 0; nb < 4; ++nb) {
        float p = __expf(s[nb][i] * scale - mnew);
        u16 pb = f32_to_bf16u(p);
        Pw[(fq * 4 + i) * KVB + nb * 16 + fr] = pb;
        rs += bf16u_to_f32(pb);  // sum the rounded values so l matches PV exactly
      }
      #pragma unroll
      for (int d = 1; d < 16; d <<= 1) rs += __shfl_xor(rs, d, 64);
      l_run[i] = l_run[i] * corr + rs;
      #pragma unroll
      for (int db = 0; db < 4; ++db) oacc[db][i] *= corr;
    }
    __syncthreads();  // P visible within wave (and keeps block uniform)

    // PV: O[q][d] += P[q][kv] * V[kv][d]; A=P from Ps, B^T = VTs[d][kv]
    #pragma unroll
    for (int ks = 0; ks < 2; ++ks) {
      bf16x8 pf = *reinterpret_cast<const bf16x8*>(&Pw[fr * KVB + ks * 32 + fq * 8]);
      #pragma unroll
      for (int db = 0; db < 4; ++db) {
        bf16x8 vf = *reinterpret_cast<const bf16x8*>(&VTs[(db * 16 + fr) * KVB + ks * 32 + fq * 8]);
        oacc[db] = __builtin_amdgcn_mfma_f32_16x16x32_bf16(pf, vf, oacc[db], 0, 0, 0);
      }
    }
    __syncthreads();  // all LDS reads done before next tile's stage
  }

  // epilogue: O /= l, write bf16 [b][q][h*64+d]
  #pragma unroll
  for (int i = 0; i < 4; ++i) {
    float inv = 1.f / l_run[i];
    size_t rowoff = base_q + (size_t)(q0 + fq * 4 + i) * DIM_;
    #pragma unroll
    for (int db = 0; db < 4; ++db)
      og[rowoff + db * 16 + fr] = f32_to_bf16u(oacc[db][i] * inv);
  }
}

// ---------------- launch ----------------
extern "C" void kernel_launch(void* const* d_in, const int* in_sizes, int n_in,
                              void* d_out, int out_size, void* d_ws, size_t ws_size,
                              hipStream_t stream) {
  (void)in_sizes; (void)n_in; (void)out_size; (void)ws_size;
  const float* x1 = (const float*)d_in[0];
  const float* x2 = (const float*)d_in[1];
  const float* Wq = (const float*)d_in[2];
  const float* bq = (const float*)d_in[3];
  const float* Wk = (const float*)d_in[4];
  const float* bk = (const float*)d_in[5];
  const float* Wv = (const float*)d_in[6];
  const float* bv = (const float*)d_in[7];
  const float* Wo = (const float*)d_in[8];
  const float* bo = (const float*)d_in[9];
  float* out = (float*)d_out;

  char* ws = (char*)d_ws;
  u16* x1b = (u16*)(ws);                       // 8 MB
  u16* x2b = (u16*)(ws + (8u  << 20));         // 8 MB
  u16* Wqb = (u16*)(ws + (16u << 20));         // 2 MB
  u16* Wkb = (u16*)(ws + (18u << 20));
  u16* Wvb = (u16*)(ws + (20u << 20));
  u16* Wob = (u16*)(ws + (22u << 20));
  u16* qb  = (u16*)(ws + (24u << 20));         // 8 MB
  u16* kb  = (u16*)(ws + (32u << 20));
  u16* vb  = (u16*)(ws + (40u << 20));
  u16* ob  = (u16*)(ws + (48u << 20));         // total 56 MB

  auto launch_cast = [&](const float* s, u16* d, int n) {
    int n4 = n / 4;
    int blocks = (n4 + 255) / 256;
    if (blocks > 2048) blocks = 2048;
    cast_f32_bf16<<<dim3(blocks), dim3(256), 0, stream>>>(s, d, n4);
  };
  launch_cast(x1, x1b, BB_ * NN_ * DIM_);
  launch_cast(x2, x2b, BB_ * MM_ * DIM_);
  launch_cast(Wq, Wqb, DIM_ * DIM_);
  launch_cast(Wk, Wkb, DIM_ * DIM_);
  launch_cast(Wv, Wvb, DIM_ * DIM_);
  launch_cast(Wo, Wob, DIM_ * DIM_);

  const int Mrows = BB_ * NN_;  // 4096
  dim3 gg(Mrows / BM, DIM_ / BN);  // (32, 8)
  gemm_bt<true ><<<gg, 256, 0, stream>>>(x1b, Wqb, bq, qb, Mrows, DIM_, DIM_);
  gemm_bt<true ><<<gg, 256, 0, stream>>>(x2b, Wkb, bk, kb, Mrows, DIM_, DIM_);
  gemm_bt<true ><<<gg, 256, 0, stream>>>(x2b, Wvb, bv, vb, Mrows, DIM_, DIM_);

  dim3 ga(NN_ / QB, NHEADS_, BB_);  // (32, 16, 2)
  attn_fwd<<<ga, 256, 0, stream>>>(qb, kb, vb, ob);

  gemm_bt<false><<<gg, 256, 0, stream>>>(ob, Wob, bo, out, Mrows, DIM_, DIM_);
}

// Round 2
// 238.142 us; speedup vs baseline: 1.3432x; 1.3432x over previous
//
#include <hip/hip_runtime.h>
#include <stdint.h>

typedef unsigned short u16;
typedef __attribute__((ext_vector_type(4))) float f32x4;
typedef __attribute__((ext_vector_type(8))) __bf16 bf16x8;
typedef __attribute__((ext_vector_type(8))) unsigned short u16x8;
typedef __attribute__((ext_vector_type(4))) unsigned short u16x4;

#define DIM_    1024
#define NHEADS_ 16
#define HD_     64
#define BB_     2
#define NN_     2048
#define MM_     2048

__device__ inline u16 f32_to_bf16u(float f) {
  union { float f; uint32_t u; } x; x.f = f;
  uint32_t r = x.u + 0x7FFFu + ((x.u >> 16) & 1u);
  return (u16)(r >> 16);
}
__device__ inline float bf16u_to_f32(u16 h) {
  union { uint32_t u; float f; } x; x.u = ((uint32_t)h) << 16;
  return x.f;
}

__device__ inline void gload_lds16(const u16* g, u16* l) {
  u16* gnc = const_cast<u16*>(g);
  __builtin_amdgcn_global_load_lds(
      (__attribute__((address_space(1))) void*)gnc,
      (__attribute__((address_space(3))) void*)l, 16, 0, 0);
}

// ---------------- cast fp32 -> bf16 (vectorized) ----------------
__global__ void cast_f32_bf16(const float* __restrict__ src, u16* __restrict__ dst, int n4) {
  int i = blockIdx.x * blockDim.x + threadIdx.x;
  int stride = gridDim.x * blockDim.x;
  for (; i < n4; i += stride) {
    float4 f = reinterpret_cast<const float4*>(src)[i];
    u16x4 u;
    u.x = f32_to_bf16u(f.x);
    u.y = f32_to_bf16u(f.y);
    u.z = f32_to_bf16u(f.z);
    u.w = f32_to_bf16u(f.w);
    reinterpret_cast<u16x4*>(dst)[i] = u;
  }
}

// ---------------- GEMM: C[M,N] = A[M,K] (bf16) * B[N,K]^T (bf16) + bias[N] ----------------
// 128x128 tile, BK=64, 4 waves (2x2). LDS tiles XOR-swizzled in 16B chunks by row&7
// (rule #21: linear LDS dest + pre-swizzled global source + swizzled ds_read).
#define BM 128
#define BN 128
#define BK 64

template <bool BF16OUT>
__global__ __launch_bounds__(256)
void gemm_bt(const u16* __restrict__ A, const u16* __restrict__ Bm,
             const float* __restrict__ bias, void* __restrict__ Cout,
             int M, int N, int K) {
  __shared__ __align__(16) u16 As[BM * BK];
  __shared__ __align__(16) u16 Bs[BN * BK];
  const int tid  = threadIdx.x;
  const int lane = tid & 63;
  const int wid  = tid >> 6;
  const int wr = wid >> 1, wc = wid & 1;
  const int fr = lane & 15, fq = lane >> 4;
  const int bm = blockIdx.x, bn = blockIdx.y;
  const int lrow = lane >> 3;                                // 0..7 row within 8-row chunk
  const int scol = (((lane & 7) ^ (lrow & 7)) * 8);          // pre-swizzled source col (u16)

  f32x4 acc[4][4];
  #pragma unroll
  for (int m = 0; m < 4; ++m)
    #pragma unroll
    for (int n = 0; n < 4; ++n)
      acc[m][n] = f32x4{0.f, 0.f, 0.f, 0.f};

  for (int k0 = 0; k0 < K; k0 += BK) {
    #pragma unroll
    for (int c = 0; c < 4; ++c) {
      int ch  = wid * 4 + c;           // 0..15
      int row = ch * 8 + lrow;         // 0..127
      gload_lds16(A  + (size_t)(bm * BM + row) * K + k0 + scol, &As[ch * 512]);
      gload_lds16(Bm + (size_t)(bn * BN + row) * K + k0 + scol, &Bs[ch * 512]);
    }
    __syncthreads();

    #pragma unroll
    for (int ks = 0; ks < 2; ++ks) {
      bf16x8 af[4], bfr[4];
      #pragma unroll
      for (int m = 0; m < 4; ++m)
        af[m] = *reinterpret_cast<const bf16x8*>(
            &As[(wr * 64 + m * 16 + fr) * BK + (((ks * 4 + fq) ^ (fr & 7)) * 8)]);
      #pragma unroll
      for (int n = 0; n < 4; ++n)
        bfr[n] = *reinterpret_cast<const bf16x8*>(
            &Bs[(wc * 64 + n * 16 + fr) * BK + (((ks * 4 + fq) ^ (fr & 7)) * 8)]);
      #pragma unroll
      for (int m = 0; m < 4; ++m)
        #pragma unroll
        for (int n = 0; n < 4; ++n)
          acc[m][n] = __builtin_amdgcn_mfma_f32_16x16x32_bf16(af[m], bfr[n], acc[m][n], 0, 0, 0);
    }
    __syncthreads();
  }

  #pragma unroll
  for (int n = 0; n < 4; ++n) {
    int col = bn * BN + wc * 64 + n * 16 + fr;
    float bv = bias[col];
    #pragma unroll
    for (int m = 0; m < 4; ++m) {
      #pragma unroll
      for (int i = 0; i < 4; ++i) {
        int row = bm * BM + wr * 64 + m * 16 + fq * 4 + i;
        float v = acc[m][n][i] + bv;
        if (BF16OUT)
          ((u16*)Cout)[(size_t)row * N + col] = f32_to_bf16u(v);
        else
          ((float*)Cout)[(size_t)row * N + col] = v;
      }
    }
  }
}

// ---------------- flash attention ----------------
// grid: (NN/64, NHEADS, BB); 256 threads = 4 waves; each wave owns 16 q-rows.
// K staged [kv][64] via global_load_lds w/ source pre-swizzle; V staged transposed
// [d][kv] via lane-per-row gather (write = whole VT row per instr); P swizzled.
#define QB 64
#define KVB 64

__global__ __launch_bounds__(256)
void attn_fwd(const u16* __restrict__ qg, const u16* __restrict__ kg,
              const u16* __restrict__ vg, u16* __restrict__ og) {
  __shared__ __align__(16) u16 Ks[KVB * HD_];
  __shared__ __align__(16) u16 VTs[HD_ * KVB];
  __shared__ __align__(16) u16 Ps[4][16 * KVB];
  const int tid = threadIdx.x, lane = tid & 63, wid = tid >> 6;
  const int fr = lane & 15, fq = lane >> 4;
  const int b = blockIdx.z, h = blockIdx.y;
  const int q0 = blockIdx.x * QB + wid * 16;
  const size_t base_q  = (size_t)b * NN_ * DIM_ + (size_t)h * HD_;
  const size_t base_kv = (size_t)b * MM_ * DIM_ + (size_t)h * HD_;
  const int lrow = lane >> 3;
  const int scol = (((lane & 7) ^ (lrow & 7)) * 8);  // pre-swizzled K source col
  const float scale = 0.125f;  // 1/sqrt(64)

  // Q fragments in registers: rows q0+fr, cols ks*32 + fq*8 + j (unswizzled, from global)
  bf16x8 qf[2];
  #pragma unroll
  for (int ks = 0; ks < 2; ++ks)
    qf[ks] = *reinterpret_cast<const bf16x8*>(qg + base_q + (size_t)(q0 + fr) * DIM_ + ks * 32 + fq * 8);

  float m_run[4] = {-INFINITY, -INFINITY, -INFINITY, -INFINITY};
  float l_run[4] = {0.f, 0.f, 0.f, 0.f};
  f32x4 oacc[4];
  #pragma unroll
  for (int db = 0; db < 4; ++db) oacc[db] = f32x4{0.f, 0.f, 0.f, 0.f};

  const int ksw = (fr & 7);            // read-side swizzle key for K/VT rows
  const int psw = (fr & 7) ^ (fr >> 3);  // read-side swizzle key for P row q=fr

  for (int kv0 = 0; kv0 < MM_; kv0 += KVB) {
    // ---- stage K: 8 KB via global_load_lds, source pre-swizzled ----
    #pragma unroll
    for (int c = 0; c < 2; ++c) {
      int ch  = wid * 2 + c;   // 0..7
      int row = ch * 8 + lrow; // 0..63
      gload_lds16(kg + base_kv + (size_t)(kv0 + row) * DIM_ + scol, &Ks[ch * 512]);
    }
    // ---- stage V transposed: lane-per-kv-row gather; per store j all 64 lanes
    //      write one VT row (consecutive u16, ~2-way). chunk swizzle key = d&7 = j.
    #pragma unroll
    for (int p = 0; p < 2; ++p) {
      int c = wid * 2 + p;  // d-chunk 0..7
      u16x8 vv = *reinterpret_cast<const u16x8*>(vg + base_kv + (size_t)(kv0 + lane) * DIM_ + c * 8);
      #pragma unroll
      for (int j = 0; j < 8; ++j)
        VTs[(c * 8 + j) * KVB + (((lane >> 3) ^ j) * 8) + (lane & 7)] = vv[j];
    }
    __syncthreads();

    // ---- QK^T: S[q=fq*4+i][kv=nb*16+fr] ----
    f32x4 s[4];
    #pragma unroll
    for (int nb = 0; nb < 4; ++nb) s[nb] = f32x4{0.f, 0.f, 0.f, 0.f};
    #pragma unroll
    for (int nb = 0; nb < 4; ++nb)
      #pragma unroll
      for (int ks = 0; ks < 2; ++ks) {
        bf16x8 kf = *reinterpret_cast<const bf16x8*>(
            &Ks[(nb * 16 + fr) * HD_ + (((ks * 4 + fq) ^ ksw) * 8)]);
        s[nb] = __builtin_amdgcn_mfma_f32_16x16x32_bf16(qf[ks], kf, s[nb], 0, 0, 0);
      }

    // ---- online softmax; P stored swizzled: slot' = slot ^ (q&7) ^ (q>>3) ----
    u16* Pw = Ps[wid];
    #pragma unroll
    for (int i = 0; i < 4; ++i) {
      float mx = fmaxf(fmaxf(s[0][i], s[1][i]), fmaxf(s[2][i], s[3][i])) * scale;
      #pragma unroll
      for (int d = 1; d < 16; d <<= 1) mx = fmaxf(mx, __shfl_xor(mx, d, 64));
      float mnew = fmaxf(m_run[i], mx);
      float corr = __expf(m_run[i] - mnew);
      m_run[i] = mnew;
      float rs = 0.f;
      const int q = fq * 4 + i;
      const int wkey = (q & 7) ^ (q >> 3);
      #pragma unroll
      for (int nb = 0; nb < 4; ++nb) {
        float p = __expf(s[nb][i] * scale - mnew);
        u16 pb = f32_to_bf16u(p);
        Pw[q * KVB + (((nb * 2 + (fr >> 3)) ^ wkey) * 8) + (fr & 7)] = pb;
        rs += bf16u_to_f32(pb);  // sum rounded values so l matches PV exactly
      }
      #pragma unroll
      for (int d = 1; d < 16; d <<= 1) rs += __shfl_xor(rs, d, 64);
      l_run[i] = l_run[i] * corr + rs;
      #pragma unroll
      for (int db = 0; db < 4; ++db) oacc[db][i] *= corr;
    }
    __syncthreads();

    // ---- PV: O[q][d] += P[q][kv] * V[kv][d]; A=P (swizzled), B^T=VT (swizzled) ----
    #pragma unroll
    for (int ks = 0; ks < 2; ++ks) {
      bf16x8 pf = *reinterpret_cast<const bf16x8*>(
          &Pw[fr * KVB + (((ks * 4 + fq) ^ psw) * 8)]);
      #pragma unroll
      for (int db = 0; db < 4; ++db) {
        bf16x8 vf = *reinterpret_cast<const bf16x8*>(
            &VTs[(db * 16 + fr) * KVB + (((ks * 4 + fq) ^ ksw) * 8)]);
        oacc[db] = __builtin_amdgcn_mfma_f32_16x16x32_bf16(pf, vf, oacc[db], 0, 0, 0);
      }
    }
    __syncthreads();
  }

  // epilogue: O /= l, write bf16 [b][q][h*64+d]
  #pragma unroll
  for (int i = 0; i < 4; ++i) {
    float inv = 1.f / l_run[i];
    size_t rowoff = base_q + (size_t)(q0 + fq * 4 + i) * DIM_;
    #pragma unroll
    for (int db = 0; db < 4; ++db)
      og[rowoff + db * 16 + fr] = f32_to_bf16u(oacc[db][i] * inv);
  }
}

// ---------------- launch ----------------
extern "C" void kernel_launch(void* const* d_in, const int* in_sizes, int n_in,
                              void* d_out, int out_size, void* d_ws, size_t ws_size,
                              hipStream_t stream) {
  (void)in_sizes; (void)n_in; (void)out_size; (void)ws_size;
  const float* x1 = (const float*)d_in[0];
  const float* x2 = (const float*)d_in[1];
  const float* Wq = (const float*)d_in[2];
  const float* bq = (const float*)d_in[3];
  const float* Wk = (const float*)d_in[4];
  const float* bk = (const float*)d_in[5];
  const float* Wv = (const float*)d_in[6];
  const float* bv = (const float*)d_in[7];
  const float* Wo = (const float*)d_in[8];
  const float* bo = (const float*)d_in[9];
  float* out = (float*)d_out;

  char* ws = (char*)d_ws;
  u16* x1b = (u16*)(ws);                       // 8 MB
  u16* x2b = (u16*)(ws + (8u  << 20));         // 8 MB
  u16* Wqb = (u16*)(ws + (16u << 20));         // 2 MB
  u16* Wkb = (u16*)(ws + (18u << 20));
  u16* Wvb = (u16*)(ws + (20u << 20));
  u16* Wob = (u16*)(ws + (22u << 20));
  u16* qb  = (u16*)(ws + (24u << 20));         // 8 MB
  u16* kb  = (u16*)(ws + (32u << 20));
  u16* vb  = (u16*)(ws + (40u << 20));
  u16* ob  = (u16*)(ws + (48u << 20));         // total 56 MB

  auto launch_cast = [&](const float* s, u16* d, int n) {
    int n4 = n / 4;
    int blocks = (n4 + 255) / 256;
    if (blocks > 2048) blocks = 2048;
    cast_f32_bf16<<<dim3(blocks), dim3(256), 0, stream>>>(s, d, n4);
  };
  launch_cast(x1, x1b, BB_ * NN_ * DIM_);
  launch_cast(x2, x2b, BB_ * MM_ * DIM_);
  launch_cast(Wq, Wqb, DIM_ * DIM_);
  launch_cast(Wk, Wkb, DIM_ * DIM_);
  launch_cast(Wv, Wvb, DIM_ * DIM_);
  launch_cast(Wo, Wob, DIM_ * DIM_);

  const int Mrows = BB_ * NN_;  // 4096
  dim3 gg(Mrows / BM, DIM_ / BN);  // (32, 8)
  gemm_bt<true ><<<gg, 256, 0, stream>>>(x1b, Wqb, bq, qb, Mrows, DIM_, DIM_);
  gemm_bt<true ><<<gg, 256, 0, stream>>>(x2b, Wkb, bk, kb, Mrows, DIM_, DIM_);
  gemm_bt<true ><<<gg, 256, 0, stream>>>(x2b, Wvb, bv, vb, Mrows, DIM_, DIM_);

  dim3 ga(NN_ / QB, NHEADS_, BB_);  // (32, 16, 2)
  attn_fwd<<<ga, 256, 0, stream>>>(qb, kb, vb, ob);

  gemm_bt<false><<<gg, 256, 0, stream>>>(ob, Wob, bo, out, Mrows, DIM_, DIM_);
}